// Round 8
// baseline (580.213 us; speedup 1.0000x reference)
//
#include <hip/hip_runtime.h>
#include <stdint.h>

#define HDIM 64
#define TDIM 512

// One wave per batch, full recurrence in one asm block, W_hh resident in
// v40-v103. Hazard model (r5/r6/r7 evidence):
//   - SALU/VALU write -> v_readlane LANE-SELECT SGPR: needs big distance
//     (r5 NaN at dist 1-2; r6 pass with s_nop4 + ~140-instr hoist). KEPT.
//   - VALU write SGPR (v_readlane) -> VALU read as constant: needs a few
//     slots (r7 NaN at dist 0-1; r6 pass at dist >=60). This round: software
//     pipeline with 16 rotating SGPRs -> write->read distance = 16 instr,
//     readlanes spaced 1:1 with fmacs (no writeback burst like r6's 64-run).
//   - trans ops (v_exp/v_rcp): keep r6's s_nop 1 (passing config).
// Accumulation order identical to r2-r6: acc = k mod 4, k ascending.
// Register map: v40-v103 W row | v104-107 accs | v111 h | v116-123 x chunks
//   s13 t-idx | s15 xt | s16-s31 rotating h-broadcast

#define RLk(k, s) "v_readlane_b32 s" #s ", v111, " #k "\n\t"
#define FMk(s, a, w) "v_fmac_f32 v" #a ", s" #s ", v" #w "\n\t"

// prologue: h[0..7] -> s16..s23
#define MAC_PRO \
  RLk(0,16) RLk(1,17) RLk(2,18) RLk(3,19) RLk(4,20) RLk(5,21) RLk(6,22) RLk(7,23)

// steady: RL(k+8) ; FM(k)  — SGPR write->read distance 16
#define MAC_PIPE \
  RLk(8,24)  FMk(16,104,40)  RLk(9,25)  FMk(17,105,41)  \
  RLk(10,26) FMk(18,106,42)  RLk(11,27) FMk(19,107,43)  \
  RLk(12,28) FMk(20,104,44)  RLk(13,29) FMk(21,105,45)  \
  RLk(14,30) FMk(22,106,46)  RLk(15,31) FMk(23,107,47)  \
  RLk(16,16) FMk(24,104,48)  RLk(17,17) FMk(25,105,49)  \
  RLk(18,18) FMk(26,106,50)  RLk(19,19) FMk(27,107,51)  \
  RLk(20,20) FMk(28,104,52)  RLk(21,21) FMk(29,105,53)  \
  RLk(22,22) FMk(30,106,54)  RLk(23,23) FMk(31,107,55)  \
  RLk(24,24) FMk(16,104,56)  RLk(25,25) FMk(17,105,57)  \
  RLk(26,26) FMk(18,106,58)  RLk(27,27) FMk(19,107,59)  \
  RLk(28,28) FMk(20,104,60)  RLk(29,29) FMk(21,105,61)  \
  RLk(30,30) FMk(22,106,62)  RLk(31,31) FMk(23,107,63)  \
  RLk(32,16) FMk(24,104,64)  RLk(33,17) FMk(25,105,65)  \
  RLk(34,18) FMk(26,106,66)  RLk(35,19) FMk(27,107,67)  \
  RLk(36,20) FMk(28,104,68)  RLk(37,21) FMk(29,105,69)  \
  RLk(38,22) FMk(30,106,70)  RLk(39,23) FMk(31,107,71)  \
  RLk(40,24) FMk(16,104,72)  RLk(41,25) FMk(17,105,73)  \
  RLk(42,26) FMk(18,106,74)  RLk(43,27) FMk(19,107,75)  \
  RLk(44,28) FMk(20,104,76)  RLk(45,29) FMk(21,105,77)  \
  RLk(46,30) FMk(22,106,78)  RLk(47,31) FMk(23,107,79)  \
  RLk(48,16) FMk(24,104,80)  RLk(49,17) FMk(25,105,81)  \
  RLk(50,18) FMk(26,106,82)  RLk(51,19) FMk(27,107,83)  \
  RLk(52,20) FMk(28,104,84)  RLk(53,21) FMk(29,105,85)  \
  RLk(54,22) FMk(30,106,86)  RLk(55,23) FMk(31,107,87)  \
  RLk(56,24) FMk(16,104,88)  RLk(57,25) FMk(17,105,89)  \
  RLk(58,26) FMk(18,106,90)  RLk(59,27) FMk(19,107,91)  \
  RLk(60,28) FMk(20,104,92)  RLk(61,29) FMk(21,105,93)  \
  RLk(62,30) FMk(22,106,94)  RLk(63,31) FMk(23,107,95)

// epilogue: FM(56..63) — min SGPR distance 9
#define MAC_EPI \
  FMk(24,104,96) FMk(25,105,97) FMk(26,106,98)  FMk(27,107,99) \
  FMk(28,104,100) FMk(29,105,101) FMk(30,106,102) FMk(31,107,103)

// tanh(z) = 1 - 2/(1+e^{2z}); literal = 2*log2(e); trans-op nops kept (r6)
#define TANH_H \
  "v_add_f32 v104, v104, v105\n\t"            \
  "v_add_f32 v106, v106, v107\n\t"            \
  "v_add_f32 v104, v104, v106\n\t"            \
  "v_mul_f32 v105, 0x4038aa3b, v104\n\t"      \
  "v_exp_f32 v105, v105\n\t"                  \
  "s_nop 1\n\t"                               \
  "v_add_f32 v105, 1.0, v105\n\t"             \
  "v_rcp_f32 v105, v105\n\t"                  \
  "s_nop 1\n\t"                               \
  "v_fma_f32 v111, -2.0, v105, 1.0\n\t"

// one 64-timestep chunk; s13 lane-select hazard: s_mov+s_nop4 at entry,
// s_add right after use (next use ~150 instr away). xt (s15) written 12
// slots before its read in the bias fma.
#define CHUNK(c, xreg) \
  "s_mov_b32 s13, 0\n\t"                      \
  "s_nop 4\n\t"                               \
  "Lc" #c "_%=:\n\t"                          \
  "v_readlane_b32 s15, " xreg ", s13\n\t"     \
  "s_add_u32 s13, s13, 1\n\t"                 \
  "v_mov_b32 v105, 0\n\t"                     \
  "v_mov_b32 v106, 0\n\t"                     \
  "v_mov_b32 v107, 0\n\t"                     \
  MAC_PRO                                     \
  "v_fma_f32 v104, s15, %[wih], %[bias]\n\t"  \
  MAC_PIPE                                    \
  MAC_EPI                                     \
  TANH_H                                      \
  "s_cmp_lt_u32 s13, 64\n\t"                  \
  "s_cbranch_scc1 Lc" #c "_%=\n\t"

__global__ __launch_bounds__(256, 2)
void rnn_asm_f32(const float* __restrict__ x,
                 const float* __restrict__ W_ih,
                 const float* __restrict__ W_hh,
                 const float* __restrict__ b_ih,
                 const float* __restrict__ b_hh,
                 const float* __restrict__ fc_w,
                 const float* __restrict__ fc_b,
                 float* __restrict__ out,
                 int B)
{
    const int lane  = threadIdx.x & 63;
    const int batch = blockIdx.x * (blockDim.x >> 6) + (threadIdx.x >> 6);
    if (batch >= B) return;   // wave-uniform (B divides grid exactly)

    const float w_ih_l = W_ih[lane];
    const float bias_l = b_ih[lane] + b_hh[lane];

    const uintptr_t xp = (uintptr_t)(x + (size_t)batch * TDIM + lane);
    const uintptr_t wp = (uintptr_t)(W_hh + (size_t)lane * HDIM);
    const uint32_t xlo = (uint32_t)xp, xhi = (uint32_t)(xp >> 32);
    const uint32_t wlo = (uint32_t)wp, whi = (uint32_t)(wp >> 32);

    float h;
    asm volatile(
        // ---- x: 8 chunks of 64 timesteps, lane j holds x[c*64+j] ----
        "v_mov_b32 v112, %[xlo]\n\t"
        "v_mov_b32 v113, %[xhi]\n\t"
        "global_load_dword v116, v[112:113], off\n\t"
        "global_load_dword v117, v[112:113], off offset:256\n\t"
        "global_load_dword v118, v[112:113], off offset:512\n\t"
        "global_load_dword v119, v[112:113], off offset:768\n\t"
        "global_load_dword v120, v[112:113], off offset:1024\n\t"
        "global_load_dword v121, v[112:113], off offset:1280\n\t"
        "global_load_dword v122, v[112:113], off offset:1536\n\t"
        "global_load_dword v123, v[112:113], off offset:1792\n\t"
        // ---- W_hh row -> v40..v103 (resident forever) ----
        "v_mov_b32 v112, %[wlo]\n\t"
        "v_mov_b32 v113, %[whi]\n\t"
        "global_load_dwordx4 v[40:43],   v[112:113], off\n\t"
        "global_load_dwordx4 v[44:47],   v[112:113], off offset:16\n\t"
        "global_load_dwordx4 v[48:51],   v[112:113], off offset:32\n\t"
        "global_load_dwordx4 v[52:55],   v[112:113], off offset:48\n\t"
        "global_load_dwordx4 v[56:59],   v[112:113], off offset:64\n\t"
        "global_load_dwordx4 v[60:63],   v[112:113], off offset:80\n\t"
        "global_load_dwordx4 v[64:67],   v[112:113], off offset:96\n\t"
        "global_load_dwordx4 v[68:71],   v[112:113], off offset:112\n\t"
        "global_load_dwordx4 v[72:75],   v[112:113], off offset:128\n\t"
        "global_load_dwordx4 v[76:79],   v[112:113], off offset:144\n\t"
        "global_load_dwordx4 v[80:83],   v[112:113], off offset:160\n\t"
        "global_load_dwordx4 v[84:87],   v[112:113], off offset:176\n\t"
        "global_load_dwordx4 v[88:91],   v[112:113], off offset:192\n\t"
        "global_load_dwordx4 v[92:95],   v[112:113], off offset:208\n\t"
        "global_load_dwordx4 v[96:99],   v[112:113], off offset:224\n\t"
        "global_load_dwordx4 v[100:103], v[112:113], off offset:240\n\t"
        "v_mov_b32 v111, 0\n\t"          // h = 0
        "s_waitcnt vmcnt(0)\n\t"
        CHUNK(0, "v116")
        CHUNK(1, "v117")
        CHUNK(2, "v118")
        CHUNK(3, "v119")
        CHUNK(4, "v120")
        CHUNK(5, "v121")
        CHUNK(6, "v122")
        CHUNK(7, "v123")
        "v_mov_b32 %[ho], v111\n\t"
        : [ho] "=v"(h)
        : [xlo] "v"(xlo), [xhi] "v"(xhi),
          [wlo] "v"(wlo), [whi] "v"(whi),
          [wih] "v"(w_ih_l), [bias] "v"(bias_l)
        : "memory", "scc", "s13", "s15",
          "s16","s17","s18","s19","s20","s21","s22","s23",
          "s24","s25","s26","s27","s28","s29","s30","s31",
          "v40","v41","v42","v43","v44","v45","v46","v47",
          "v48","v49","v50","v51","v52","v53","v54","v55",
          "v56","v57","v58","v59","v60","v61","v62","v63",
          "v64","v65","v66","v67","v68","v69","v70","v71",
          "v72","v73","v74","v75","v76","v77","v78","v79",
          "v80","v81","v82","v83","v84","v85","v86","v87",
          "v88","v89","v90","v91","v92","v93","v94","v95",
          "v96","v97","v98","v99","v100","v101","v102","v103",
          "v104","v105","v106","v107","v108","v109","v110","v111",
          "v112","v113","v114","v115","v116","v117","v118","v119",
          "v120","v121","v122","v123");

    // out[batch] = sum_i h[i]*fc_w[i] + fc_b  (wave butterfly reduce)
    float v = h * fc_w[lane];
#pragma unroll
    for (int off = 32; off > 0; off >>= 1)
        v += __shfl_xor(v, off, 64);

    if (lane == 0)
        out[batch] = v + fc_b[0];
}

extern "C" void kernel_launch(void* const* d_in, const int* in_sizes, int n_in,
                              void* d_out, int out_size, void* d_ws, size_t ws_size,
                              hipStream_t stream)
{
    const float* x    = (const float*)d_in[0];
    const float* W_ih = (const float*)d_in[1];
    const float* W_hh = (const float*)d_in[2];
    const float* b_ih = (const float*)d_in[3];
    const float* b_hh = (const float*)d_in[4];
    const float* fc_w = (const float*)d_in[5];
    const float* fc_b = (const float*)d_in[6];
    float* out = (float*)d_out;

    const int B = in_sizes[0] / TDIM;          // x is (B, T, 1)
    const int wavesPerBlock = 4;
    const int blocks = (B + wavesPerBlock - 1) / wavesPerBlock;

    rnn_asm_f32<<<blocks, wavesPerBlock * 64, 0, stream>>>(
        x, W_ih, W_hh, b_ih, b_hh, fc_w, fc_b, out, B);
}